// Round 1
// baseline (423.488 us; speedup 1.0000x reference)
//
#include <hip/hip_runtime.h>
#include <math.h>

// ---------------------------------------------------------------------------
// EstimatorQNNHybrid: CNN (conv1->pool->conv2->pool->avg6x6->fc1->fc2)
//  -> BatchNorm(train) -> 4-qubit product-state encoder + fixed 16x16 unitary
//  -> <Z_w> -> BatchNorm(train) -> sum.
//
// Pipeline:
//   K1 k_cnn     : per-sample CNN -> out_pre   (stored in d_out, 8192x4)
//   K2 k_stats   : BN1 stats (blocks 0-3) + build fused 16x16 complex matrix M
//                  for the whole fixed quantum tail (block 4)
//   K3 k_quantum : per-sample BN1 -> encoder product state -> M*psi -> <Z_w>
//   K4 k_stats   : BN2 stats
//   K5 k_final   : d_out[i] = bn1(out_pre[i]) + bn2(q_pre[i])   (in-place)
//
// ws usage: q_pre 32768 + ss1 8 + ss2 8 + M 512 floats = ~133 KB.
// ---------------------------------------------------------------------------

__device__ __forceinline__ float2 cmul(float2 a, float2 b) {
    return make_float2(a.x * b.x - a.y * b.y, a.x * b.y + a.y * b.x);
}
__device__ __forceinline__ float2 cadd(float2 a, float2 b) {
    return make_float2(a.x + b.x, a.y + b.y);
}

// ========================= K1: fused CNN per sample =========================
__global__ __launch_bounds__(256) void k_cnn(
    const float* __restrict__ x,
    const float* __restrict__ w1, const float* __restrict__ b1,
    const float* __restrict__ w2, const float* __restrict__ b2,
    const float* __restrict__ fw1, const float* __restrict__ fb1,
    const float* __restrict__ fw2, const float* __restrict__ fb2,
    float* __restrict__ out_pre)
{
    __shared__ __align__(16) float xs[1024];    // 32x32 zero-padded input (data at [1..28][1..28])
    __shared__ __align__(16) float h1s[2048];   // 8 ch x 16x16 zero-padded (data at [1..14][1..14])
    __shared__ __align__(16) float h2s[16 * 49];
    __shared__ __align__(16) float w1s[96];     // 8 x (9 padded to 12)
    __shared__ __align__(16) float w2s[1536];   // 128 x (9 padded to 12)
    __shared__ float b1s[8], b2s[16];
    __shared__ __align__(16) float fw1s[1024];
    __shared__ float fb1s[64];
    __shared__ __align__(16) float fw2s[256];
    __shared__ float fb2s[4];
    __shared__ float pool_s[16], fs[64];

    const int t = threadIdx.x;
    const int b = blockIdx.x;
    const float* xg = x + b * 784;

    // ---- phase A: zero padded tiles + stage weights ----
    for (int i = t; i < 1024; i += 256) xs[i] = 0.f;
    for (int i = t; i < 2048; i += 256) h1s[i] = 0.f;
    for (int i = t; i < 72;   i += 256) w1s[(i / 9) * 12 + (i % 9)] = w1[i];
    for (int i = t; i < 1152; i += 256) w2s[(i / 9) * 12 + (i % 9)] = w2[i];
    for (int i = t; i < 1024; i += 256) fw1s[i] = fw1[i];
    if (t < 8)  b1s[t] = b1[t];
    if (t < 16) b2s[t] = b2[t];
    if (t < 64) fb1s[t] = fb1[t];
    fw2s[t] = fw2[t];
    if (t < 4)  fb2s[t] = fb2[t];
    __syncthreads();

    // ---- phase B: fill input interior ----
    for (int i = t; i < 784; i += 256) {
        int yy = i / 28, xx = i % 28;
        xs[(yy + 1) * 32 + xx + 1] = xg[i];
    }
    __syncthreads();

    // ---- conv1 (1->8ch, 3x3, pad1) + relu + 2x2 maxpool -> h1 [8][14][14] ----
    // tasks: 8c x 14py x 4 px-groups {0,4,8,12} = 448
    for (int tau = t; tau < 448; tau += 256) {
        int c = tau / 56;
        int rem = tau % 56;
        int py = rem >> 2;
        int q = rem & 3;
        int px0 = q * 4;                 // group of up to 4 pooled px
        float wv[9];
        #pragma unroll
        for (int k = 0; k < 9; ++k) wv[k] = w1s[c * 12 + k];
        float rbuf[4][10];
        #pragma unroll
        for (int dr = 0; dr < 4; ++dr) {
            int base = (2 * py + dr) * 32 + 2 * px0;   // 16B aligned
            float4 a  = *(const float4*)&xs[base];
            float4 bb = *(const float4*)&xs[base + 4];
            float2 cc = *(const float2*)&xs[base + 8];
            rbuf[dr][0] = a.x;  rbuf[dr][1] = a.y;  rbuf[dr][2] = a.z;  rbuf[dr][3] = a.w;
            rbuf[dr][4] = bb.x; rbuf[dr][5] = bb.y; rbuf[dr][6] = bb.z; rbuf[dr][7] = bb.w;
            rbuf[dr][8] = cc.x; rbuf[dr][9] = cc.y;
        }
        float sums[4][2][2];
        #pragma unroll
        for (int p = 0; p < 4; ++p)
            #pragma unroll
            for (int dy = 0; dy < 2; ++dy)
                #pragma unroll
                for (int dx = 0; dx < 2; ++dx) sums[p][dy][dx] = 0.f;
        #pragma unroll
        for (int ky = 0; ky < 3; ++ky)
            #pragma unroll
            for (int kx = 0; kx < 3; ++kx) {
                float w = wv[ky * 3 + kx];
                #pragma unroll
                for (int p = 0; p < 4; ++p)
                    #pragma unroll
                    for (int dy = 0; dy < 2; ++dy)
                        #pragma unroll
                        for (int dx = 0; dx < 2; ++dx)
                            sums[p][dy][dx] = fmaf(rbuf[dy + ky][2 * p + dx + kx], w, sums[p][dy][dx]);
            }
        float bias = b1s[c];
        #pragma unroll
        for (int p = 0; p < 4; ++p) {
            int px = px0 + p;
            if (px < 14) {
                float m = fmaxf(fmaxf(sums[p][0][0], sums[p][0][1]),
                                fmaxf(sums[p][1][0], sums[p][1][1]));
                h1s[c * 256 + (py + 1) * 16 + px + 1] = fmaxf(m + bias, 0.f);
            }
        }
    }
    __syncthreads();

    // ---- conv2 (8->16ch) + relu + 2x2 maxpool -> h2 [16][7][7] ----
    // tasks: 16o x 7py x 2 px-halves = 224
    if (t < 224) {
        int o = t / 14;
        int rem = t % 14;
        int py = rem >> 1;
        int half = rem & 1;
        int px0 = half * 4;              // px 0..3 or 4..6
        float sums[4][2][2];
        #pragma unroll
        for (int p = 0; p < 4; ++p)
            #pragma unroll
            for (int dy = 0; dy < 2; ++dy)
                #pragma unroll
                for (int dx = 0; dx < 2; ++dx) sums[p][dy][dx] = 0.f;
        #pragma unroll 2
        for (int i = 0; i < 8; ++i) {
            float wv[9];
            #pragma unroll
            for (int k = 0; k < 9; ++k) wv[k] = w2s[(o * 8 + i) * 12 + k];
            float rbuf[4][10];
            #pragma unroll
            for (int dr = 0; dr < 4; ++dr) {
                int base = i * 256 + (2 * py + dr) * 16 + 2 * px0;  // 16B aligned
                float4 a  = *(const float4*)&h1s[base];
                float4 bb = *(const float4*)&h1s[base + 4];
                rbuf[dr][0] = a.x;  rbuf[dr][1] = a.y;  rbuf[dr][2] = a.z;  rbuf[dr][3] = a.w;
                rbuf[dr][4] = bb.x; rbuf[dr][5] = bb.y; rbuf[dr][6] = bb.z; rbuf[dr][7] = bb.w;
                if (half == 0) {
                    float2 cc = *(const float2*)&h1s[base + 8];
                    rbuf[dr][8] = cc.x; rbuf[dr][9] = cc.y;
                } else {
                    rbuf[dr][8] = 0.f; rbuf[dr][9] = 0.f;
                }
            }
            #pragma unroll
            for (int ky = 0; ky < 3; ++ky)
                #pragma unroll
                for (int kx = 0; kx < 3; ++kx) {
                    float w = wv[ky * 3 + kx];
                    #pragma unroll
                    for (int p = 0; p < 4; ++p)
                        #pragma unroll
                        for (int dy = 0; dy < 2; ++dy)
                            #pragma unroll
                            for (int dx = 0; dx < 2; ++dx)
                                sums[p][dy][dx] = fmaf(rbuf[dy + ky][2 * p + dx + kx], w, sums[p][dy][dx]);
                }
        }
        float bias = b2s[o];
        #pragma unroll
        for (int p = 0; p < 4; ++p) {
            int px = px0 + p;
            if (px < 7) {
                float m = fmaxf(fmaxf(sums[p][0][0], sums[p][0][1]),
                                fmaxf(sums[p][1][0], sums[p][1][1]));
                h2s[o * 49 + py * 7 + px] = fmaxf(m + bias, 0.f);
            }
        }
    }
    __syncthreads();

    // ---- avg over [:6,:6] -> pooled [16] ----
    if (t < 16) {
        float s = 0.f;
        #pragma unroll
        for (int py = 0; py < 6; ++py)
            #pragma unroll
            for (int px = 0; px < 6; ++px)
                s += h2s[t * 49 + py * 7 + px];
        pool_s[t] = s * (1.f / 36.f);
    }
    __syncthreads();

    // ---- fc1 (16->64) + relu ----
    if (t < 64) {
        float acc = fb1s[t];
        #pragma unroll
        for (int c = 0; c < 16; ++c) acc = fmaf(pool_s[c], fw1s[t * 16 + c], acc);
        fs[t] = fmaxf(acc, 0.f);
    }
    __syncthreads();

    // ---- fc2 (64->4) ----
    if (t < 4) {
        float acc = fb2s[t];
        #pragma unroll
        for (int j = 0; j < 64; ++j) acc = fmaf(fs[j], fw2s[t * 64 + j], acc);
        out_pre[b * 4 + t] = acc;
    }
}

// ============ K2/K4: BN stats (blocks 0-3) + optional M build (block 4) =====
__device__ __forceinline__ void apply_1q(const float2* src, float2* dst, int t,
                                         float2 g00, float2 g01, float2 g10, float2 g11, int p)
{
    int j = t >> 4, i = t & 15;
    int jb = (j >> p) & 1;
    int k0 = j & ~(1 << p);
    int k1 = j | (1 << p);
    float2 a0 = src[k0 * 16 + i], a1 = src[k1 * 16 + i];
    float2 r = jb ? cadd(cmul(g10, a0), cmul(g11, a1))
                  : cadd(cmul(g00, a0), cmul(g01, a1));
    dst[j * 16 + i] = r;
}

__device__ __forceinline__ void apply_ctrl(const float2* src, float2* dst, int t,
                                           float2 g00, float2 g01, float2 g10, float2 g11,
                                           int pc, int pt)
{
    int j = t >> 4, i = t & 15;
    float2 r;
    if (((j >> pc) & 1) == 0) {
        r = src[j * 16 + i];
    } else {
        int jb = (j >> pt) & 1;
        int k0 = j & ~(1 << pt);
        int k1 = j | (1 << pt);
        float2 a0 = src[k0 * 16 + i], a1 = src[k1 * 16 + i];
        r = jb ? cadd(cmul(g10, a0), cmul(g11, a1))
               : cadd(cmul(g00, a0), cmul(g01, a1));
    }
    dst[j * 16 + i] = r;
}

__global__ __launch_bounds__(256) void k_stats(
    const float* __restrict__ vals,      // [8192,4]
    const float* __restrict__ g, const float* __restrict__ bb,
    float* __restrict__ scale_shift,     // [8]: scale[4], shift[4]
    int build_m,
    const float* __restrict__ theta,
    const float* __restrict__ u_re, const float* __restrict__ u_im,
    float* __restrict__ m_out)           // [512] = 16x16 complex
{
    __shared__ float red[8];
    __shared__ float2 A[256], B[256];
    const int t = threadIdx.x;

    if (blockIdx.x < 4) {
        const int c = blockIdx.x;
        float sum = 0.f;
        for (int i = t; i < 8192; i += 256) sum += vals[i * 4 + c];
        #pragma unroll
        for (int off = 32; off > 0; off >>= 1) sum += __shfl_down(sum, off, 64);
        int wid = t >> 6;
        if ((t & 63) == 0) red[wid] = sum;
        __syncthreads();
        float mean = (red[0] + red[1] + red[2] + red[3]) * (1.f / 8192.f);
        float va = 0.f;
        for (int i = t; i < 8192; i += 256) {
            float d = vals[i * 4 + c] - mean;
            va += d * d;
        }
        #pragma unroll
        for (int off = 32; off > 0; off >>= 1) va += __shfl_down(va, off, 64);
        if ((t & 63) == 0) red[4 + wid] = va;
        __syncthreads();
        if (t == 0) {
            float var = (red[4] + red[5] + red[6] + red[7]) * (1.f / 8192.f);
            float sc = g[c] * rsqrtf(var + 1e-5f);
            scale_shift[c] = sc;
            scale_shift[4 + c] = bb[c] - mean * sc;
        }
    } else if (build_m) {
        // Fold the fixed quantum tail into M = CX * SX * H * CRX * RZ * RY * RX * U
        A[t] = make_float2(u_re[t], u_im[t]);
        float th0 = theta[0], th1 = theta[1], th2 = theta[2], th3 = theta[3];
        __syncthreads();
        float c0 = cosf(0.5f * th0), s0 = sinf(0.5f * th0);
        apply_1q(A, B, t, make_float2(c0, 0), make_float2(0, -s0),
                          make_float2(0, -s0), make_float2(c0, 0), 3);   // RX(th0) wire0
        __syncthreads();
        float c1 = cosf(0.5f * th1), s1 = sinf(0.5f * th1);
        apply_1q(B, A, t, make_float2(c1, 0), make_float2(-s1, 0),
                          make_float2(s1, 0), make_float2(c1, 0), 2);    // RY(th1) wire1
        __syncthreads();
        float c2 = cosf(0.5f * th2), s2 = sinf(0.5f * th2);
        apply_1q(A, B, t, make_float2(c2, -s2), make_float2(0, 0),
                          make_float2(0, 0), make_float2(c2, s2), 1);    // RZ(th2) wire2
        __syncthreads();
        float c3 = cosf(0.5f * th3), s3 = sinf(0.5f * th3);
        apply_ctrl(B, A, t, make_float2(c3, 0), make_float2(0, -s3),
                            make_float2(0, -s3), make_float2(c3, 0), 3, 0); // CRX ctrl w0 tgt w3
        __syncthreads();
        const float hh = 0.70710678118654752440f;
        apply_1q(A, B, t, make_float2(hh, 0), make_float2(hh, 0),
                          make_float2(hh, 0), make_float2(-hh, 0), 0);   // H wire3
        __syncthreads();
        apply_1q(B, A, t, make_float2(0.5f, 0.5f), make_float2(0.5f, -0.5f),
                          make_float2(0.5f, -0.5f), make_float2(0.5f, 0.5f), 1); // SX wire2
        __syncthreads();
        apply_ctrl(A, B, t, make_float2(0, 0), make_float2(1, 0),
                            make_float2(1, 0), make_float2(0, 0), 0, 3); // CX ctrl w3 tgt w0
        __syncthreads();
        m_out[2 * t]     = B[t].x;
        m_out[2 * t + 1] = B[t].y;
    }
}

// ================= K3: per-sample quantum circuit (1 thread/sample) =========
__global__ __launch_bounds__(256) void k_quantum(
    const float* __restrict__ out_pre,
    const float* __restrict__ ss1,       // scale[4], shift[4]
    const float* __restrict__ m,         // [512]
    float* __restrict__ q_pre)
{
    __shared__ float2 Ms[256];
    const int t = threadIdx.x;
    Ms[t] = make_float2(m[2 * t], m[2 * t + 1]);
    __syncthreads();
    const int sidx = blockIdx.x * 256 + t;

    // encoder: per-wire v = RY(a) RX(a) RZ(a) RY(a) |0>  (product state)
    float2 v[4][2];
    #pragma unroll
    for (int w = 0; w < 4; ++w) {
        float a = fmaf(ss1[w], out_pre[sidx * 4 + w], ss1[4 + w]);
        float s, c;
        __sincosf(0.5f * a, &s, &c);
        float2 v0 = make_float2(c * c, -c * s);   // RZ applied to RY|0> = (c,s)
        float2 v1 = make_float2(s * c, s * s);
        float2 n0 = make_float2(c * v0.x + s * v1.y, c * v0.y - s * v1.x);   // RX
        float2 n1 = make_float2(s * v0.y + c * v1.x, -s * v0.x + c * v1.y);
        v[w][0] = make_float2(c * n0.x - s * n1.x, c * n0.y - s * n1.y);     // RY
        v[w][1] = make_float2(s * n0.x + c * n1.x, s * n0.y + c * n1.y);
    }
    float2 st[16];
    #pragma unroll
    for (int idx = 0; idx < 16; ++idx) {
        float2 p = cmul(v[0][(idx >> 3) & 1], v[1][(idx >> 2) & 1]);
        p = cmul(p, v[2][(idx >> 1) & 1]);
        st[idx] = cmul(p, v[3][idx & 1]);
    }
    float q0 = 0.f, q1 = 0.f, q2 = 0.f, q3 = 0.f;
    #pragma unroll
    for (int j = 0; j < 16; ++j) {
        float2 acc = make_float2(0.f, 0.f);
        #pragma unroll
        for (int i = 0; i < 16; ++i) {
            float2 mm = Ms[j * 16 + i];
            acc.x = fmaf(mm.x, st[i].x, acc.x);
            acc.x = fmaf(-mm.y, st[i].y, acc.x);
            acc.y = fmaf(mm.x, st[i].y, acc.y);
            acc.y = fmaf(mm.y, st[i].x, acc.y);
        }
        float pr = acc.x * acc.x + acc.y * acc.y;
        q0 += ((j >> 3) & 1) ? -pr : pr;
        q1 += ((j >> 2) & 1) ? -pr : pr;
        q2 += ((j >> 1) & 1) ? -pr : pr;
        q3 += (j & 1) ? -pr : pr;
    }
    q_pre[sidx * 4 + 0] = q0;
    q_pre[sidx * 4 + 1] = q1;
    q_pre[sidx * 4 + 2] = q2;
    q_pre[sidx * 4 + 3] = q3;
}

// ================= K5: final combine (in-place over d_out) ==================
__global__ __launch_bounds__(256) void k_final(
    float* __restrict__ out_pre,         // == d_out
    const float* __restrict__ q_pre,
    const float* __restrict__ ss1,
    const float* __restrict__ ss2)
{
    int i = blockIdx.x * 256 + threadIdx.x;    // < 32768
    int c = i & 3;
    float a = fmaf(ss1[c], out_pre[i], ss1[4 + c]);
    float b = fmaf(ss2[c], q_pre[i], ss2[4 + c]);
    out_pre[i] = a + b;
}

// ===========================================================================
extern "C" void kernel_launch(void* const* d_in, const int* in_sizes, int n_in,
                              void* d_out, int out_size, void* d_ws, size_t ws_size,
                              hipStream_t stream)
{
    const float* x     = (const float*)d_in[0];
    const float* w1    = (const float*)d_in[1];
    const float* b1    = (const float*)d_in[2];
    const float* w2    = (const float*)d_in[3];
    const float* b2    = (const float*)d_in[4];
    const float* fw1   = (const float*)d_in[5];
    const float* fb1   = (const float*)d_in[6];
    const float* fw2   = (const float*)d_in[7];
    const float* fb2   = (const float*)d_in[8];
    const float* ng    = (const float*)d_in[9];
    const float* nb    = (const float*)d_in[10];
    const float* theta = (const float*)d_in[11];
    const float* ure   = (const float*)d_in[12];
    const float* uim   = (const float*)d_in[13];
    const float* qg    = (const float*)d_in[14];
    const float* qb    = (const float*)d_in[15];

    float* out_pre = (float*)d_out;        // reuse d_out as pre-BN logits buffer
    float* ws      = (float*)d_ws;
    float* q_pre   = ws;                   // 32768 floats
    float* ss1     = ws + 32768;           // 8 floats
    float* ss2     = ws + 32776;           // 8 floats
    float* M       = ws + 32784;           // 512 floats

    k_cnn<<<8192, 256, 0, stream>>>(x, w1, b1, w2, b2, fw1, fb1, fw2, fb2, out_pre);
    k_stats<<<5, 256, 0, stream>>>(out_pre, ng, nb, ss1, 1, theta, ure, uim, M);
    k_quantum<<<32, 256, 0, stream>>>(out_pre, ss1, M, q_pre);
    k_stats<<<4, 256, 0, stream>>>(q_pre, qg, qb, ss2, 0, theta, ure, uim, M);
    k_final<<<128, 256, 0, stream>>>(out_pre, q_pre, ss1, ss2);
}

// Round 2
// 354.091 us; speedup vs baseline: 1.1960x; 1.1960x over previous
//
#include <hip/hip_runtime.h>
#include <math.h>

// ---------------------------------------------------------------------------
// EstimatorQNNHybrid, round 2: conflict-free LDS layouts + fused BN stats.
//   memset(bins, 0)
//   K1 k_cnn     : per-sample CNN -> out_pre (d_out) + atomic BN1 partials
//   K2 k_quantum : reduce BN1 bins + build fused 16x16 M + per-sample quantum
//                  -> q_pre + per-block BN2 partials
//   K3 k_final   : reduce both bin sets -> d_out = bn1(out_pre)+bn2(q_pre)
//
// LDS strides chosen so row stride mod 32 banks rotates (36, 20 = 4 mod 8;
// 13/17/65 odd) -> ~2 lanes/bank (free on wave64).
// ws: bins1[256] bins2[256] q_pre[32768] floats = 133,120 B.
// ---------------------------------------------------------------------------

#define XS_S 36      // padded 30x36 input tile
#define H1_S 20      // padded 16x20 per-channel conv1 output
#define W1_S 13
#define W2_S 13
#define FW1_S 17
#define FW2_S 65

__device__ __forceinline__ float2 cmul(float2 a, float2 b) {
    return make_float2(a.x * b.x - a.y * b.y, a.x * b.y + a.y * b.x);
}
__device__ __forceinline__ float2 cadd(float2 a, float2 b) {
    return make_float2(a.x + b.x, a.y + b.y);
}

// ========================= K1: fused CNN per sample =========================
__global__ __launch_bounds__(256) void k_cnn(
    const float* __restrict__ x,
    const float* __restrict__ w1, const float* __restrict__ b1,
    const float* __restrict__ w2, const float* __restrict__ b2,
    const float* __restrict__ fw1, const float* __restrict__ fb1,
    const float* __restrict__ fw2, const float* __restrict__ fb2,
    float* __restrict__ out_pre, float* __restrict__ bins1)
{
    __shared__ __align__(16) float xs[30 * XS_S];       // 1080
    __shared__ __align__(16) float h1s[8 * 16 * H1_S];  // 2560
    __shared__ __align__(16) float h2s[16 * 49];
    __shared__ float w1s[8 * W1_S];
    __shared__ float w2s[128 * W2_S];                   // 1664
    __shared__ float b1s[8], b2s[16];
    __shared__ float fw1s[64 * FW1_S];                  // 1088
    __shared__ float fb1s[64];
    __shared__ float fw2s[4 * FW2_S];                   // 260
    __shared__ float fb2s[4];
    __shared__ float pool_s[16], fs[64];

    const int t = threadIdx.x;
    const int b = blockIdx.x;
    const float* xg = x + b * 784;

    // ---- zero padded tiles + stage weights (conflict-free strides) ----
    for (int i = t; i < 30 * XS_S; i += 256) xs[i] = 0.f;
    for (int i = t; i < 8 * 16 * H1_S; i += 256) h1s[i] = 0.f;
    for (int i = t; i < 72;   i += 256) w1s[(i / 9) * W1_S + (i % 9)] = w1[i];
    for (int i = t; i < 1152; i += 256) w2s[(i / 9) * W2_S + (i % 9)] = w2[i];
    for (int i = t; i < 1024; i += 256) fw1s[(i >> 4) * FW1_S + (i & 15)] = fw1[i];
    fw2s[(t >> 6) * FW2_S + (t & 63)] = fw2[t];
    if (t < 8)  b1s[t] = b1[t];
    if (t < 16) b2s[t] = b2[t];
    if (t < 64) fb1s[t] = fb1[t];
    if (t < 4)  fb2s[t] = fb2[t];
    __syncthreads();

    // ---- fill input interior: data at rows 1..28, cols 1..28 ----
    for (int i = t; i < 784; i += 256) {
        int yy = i / 28, xx = i % 28;
        xs[(yy + 1) * XS_S + xx + 1] = xg[i];
    }
    __syncthreads();

    // ---- conv1 (1->8) + relu + 2x2 maxpool: 196 (py,px) tasks, 8ch each ----
    if (t < 196) {
        const int py = t / 14, px = t % 14;
        float patch[4][4];
        #pragma unroll
        for (int dr = 0; dr < 4; ++dr) {
            int base = (2 * py + dr) * XS_S + 2 * px;       // 8B aligned
            float2 a = *(const float2*)&xs[base];
            float2 c = *(const float2*)&xs[base + 2];
            patch[dr][0] = a.x; patch[dr][1] = a.y;
            patch[dr][2] = c.x; patch[dr][3] = c.y;
        }
        for (int c = 0; c < 8; ++c) {
            float wv[9];
            #pragma unroll
            for (int k = 0; k < 9; ++k) wv[k] = w1s[c * W1_S + k];   // broadcast
            float s00 = 0.f, s01 = 0.f, s10 = 0.f, s11 = 0.f;
            #pragma unroll
            for (int ky = 0; ky < 3; ++ky)
                #pragma unroll
                for (int kx = 0; kx < 3; ++kx) {
                    float w = wv[ky * 3 + kx];
                    s00 = fmaf(patch[ky][kx],         w, s00);
                    s01 = fmaf(patch[ky][kx + 1],     w, s01);
                    s10 = fmaf(patch[ky + 1][kx],     w, s10);
                    s11 = fmaf(patch[ky + 1][kx + 1], w, s11);
                }
            float m = fmaxf(fmaxf(s00, s01), fmaxf(s10, s11)) + b1s[c];
            h1s[c * 16 * H1_S + (py + 1) * H1_S + (px + 1)] = fmaxf(m, 0.f);
        }
    }
    __syncthreads();

    // ---- conv2 (8->16) + relu + 2x2 maxpool: 224 (oc,py,half) tasks ----
    if (t < 224) {
        const int o = t / 14;
        const int rem = t % 14;
        const int py = rem >> 1;
        const int h = rem & 1;
        const int px0 = h * 4;
        float sums[4][2][2];
        #pragma unroll
        for (int p = 0; p < 4; ++p)
            #pragma unroll
            for (int dy = 0; dy < 2; ++dy)
                #pragma unroll
                for (int dx = 0; dx < 2; ++dx) sums[p][dy][dx] = 0.f;
        for (int ic = 0; ic < 8; ++ic) {
            float wv[9];
            #pragma unroll
            for (int k = 0; k < 9; ++k) wv[k] = w2s[(o * 8 + ic) * W2_S + k];
            float rbuf[4][10];
            #pragma unroll
            for (int dr = 0; dr < 4; ++dr) {
                int base = ic * 16 * H1_S + (2 * py + dr) * H1_S + 8 * h;  // 16B aligned
                float4 a = *(const float4*)&h1s[base];
                float4 c = *(const float4*)&h1s[base + 4];
                float2 d = *(const float2*)&h1s[base + 8];   // zeros when h=1 (pad)
                rbuf[dr][0] = a.x; rbuf[dr][1] = a.y; rbuf[dr][2] = a.z; rbuf[dr][3] = a.w;
                rbuf[dr][4] = c.x; rbuf[dr][5] = c.y; rbuf[dr][6] = c.z; rbuf[dr][7] = c.w;
                rbuf[dr][8] = d.x; rbuf[dr][9] = d.y;
            }
            #pragma unroll
            for (int ky = 0; ky < 3; ++ky)
                #pragma unroll
                for (int kx = 0; kx < 3; ++kx) {
                    float w = wv[ky * 3 + kx];
                    #pragma unroll
                    for (int p = 0; p < 4; ++p)
                        #pragma unroll
                        for (int dy = 0; dy < 2; ++dy)
                            #pragma unroll
                            for (int dx = 0; dx < 2; ++dx)
                                sums[p][dy][dx] = fmaf(rbuf[dy + ky][2 * p + dx + kx], w, sums[p][dy][dx]);
                }
        }
        float bias = b2s[o];
        #pragma unroll
        for (int p = 0; p < 4; ++p) {
            int px = px0 + p;
            if (px < 7) {
                float m = fmaxf(fmaxf(sums[p][0][0], sums[p][0][1]),
                                fmaxf(sums[p][1][0], sums[p][1][1]));
                h2s[o * 49 + py * 7 + px] = fmaxf(m + bias, 0.f);
            }
        }
    }
    __syncthreads();

    // ---- avg over [:6,:6] ----
    if (t < 16) {
        float s = 0.f;
        #pragma unroll
        for (int py = 0; py < 6; ++py)
            #pragma unroll
            for (int px = 0; px < 6; ++px)
                s += h2s[t * 49 + py * 7 + px];
        pool_s[t] = s * (1.f / 36.f);
    }
    __syncthreads();

    // ---- fc1 (16->64) + relu ----
    if (t < 64) {
        float acc = fb1s[t];
        #pragma unroll
        for (int c = 0; c < 16; ++c) acc = fmaf(pool_s[c], fw1s[t * FW1_S + c], acc);
        fs[t] = fmaxf(acc, 0.f);
    }
    __syncthreads();

    // ---- fc2 (64->4) + BN1 partials ----
    if (t < 4) {
        float acc = fb2s[t];
        #pragma unroll
        for (int j = 0; j < 64; ++j) acc = fmaf(fs[j], fw2s[t * FW2_S + j], acc);
        out_pre[b * 4 + t] = acc;
        int bin = (b & 31) << 3;
        atomicAdd(&bins1[bin + t], acc);
        atomicAdd(&bins1[bin + 4 + t], acc * acc);
    }
}

// ================= helpers for fixed-gate folding ==========================
__device__ __forceinline__ void apply_1q(const float2* src, float2* dst, int t,
                                         float2 g00, float2 g01, float2 g10, float2 g11, int p)
{
    int j = t >> 4, i = t & 15;
    int jb = (j >> p) & 1;
    int k0 = j & ~(1 << p);
    int k1 = j | (1 << p);
    float2 a0 = src[k0 * 16 + i], a1 = src[k1 * 16 + i];
    float2 r = jb ? cadd(cmul(g10, a0), cmul(g11, a1))
                  : cadd(cmul(g00, a0), cmul(g01, a1));
    dst[j * 16 + i] = r;
}

__device__ __forceinline__ void apply_ctrl(const float2* src, float2* dst, int t,
                                           float2 g00, float2 g01, float2 g10, float2 g11,
                                           int pc, int pt)
{
    int j = t >> 4, i = t & 15;
    float2 r;
    if (((j >> pc) & 1) == 0) {
        r = src[j * 16 + i];
    } else {
        int jb = (j >> pt) & 1;
        int k0 = j & ~(1 << pt);
        int k1 = j | (1 << pt);
        float2 a0 = src[k0 * 16 + i], a1 = src[k1 * 16 + i];
        r = jb ? cadd(cmul(g10, a0), cmul(g11, a1))
               : cadd(cmul(g00, a0), cmul(g01, a1));
    }
    dst[j * 16 + i] = r;
}

// ====== K2: BN1 reduce + M build + per-sample quantum + BN2 partials =======
__global__ __launch_bounds__(256) void k_quantum(
    const float* __restrict__ out_pre,
    const float* __restrict__ bins1,
    const float* __restrict__ ng, const float* __restrict__ nb,
    const float* __restrict__ theta,
    const float* __restrict__ u_re, const float* __restrict__ u_im,
    float* __restrict__ q_pre, float* __restrict__ bins2)
{
    __shared__ float red[256];
    __shared__ float ss1[8];
    __shared__ float2 A[256], B[256];
    __shared__ float2 Ms[256];
    const int t = threadIdx.x;

    red[t] = bins1[t];
    A[t] = make_float2(u_re[t], u_im[t]);
    float th0 = theta[0], th1 = theta[1], th2 = theta[2], th3 = theta[3];
    __syncthreads();

    if (t < 8) {                           // reduce 32 bins (wave 0, lockstep)
        float s = 0.f;
        for (int bb = 0; bb < 32; ++bb) s += red[bb * 8 + t];
        red[t] = s;
    }
    if (t < 4) {
        float mean = red[t] * (1.f / 8192.f);
        float var = red[4 + t] * (1.f / 8192.f) - mean * mean;
        float sc = ng[t] * rsqrtf(var + 1e-5f);
        ss1[t] = sc;
        ss1[4 + t] = nb[t] - mean * sc;
    }

    // fold fixed tail: M = CX * SX * H * CRX * RZ * RY * RX * U
    float c0 = cosf(0.5f * th0), s0 = sinf(0.5f * th0);
    apply_1q(A, B, t, make_float2(c0, 0), make_float2(0, -s0),
                      make_float2(0, -s0), make_float2(c0, 0), 3);   // RX wire0
    __syncthreads();
    float c1 = cosf(0.5f * th1), s1 = sinf(0.5f * th1);
    apply_1q(B, A, t, make_float2(c1, 0), make_float2(-s1, 0),
                      make_float2(s1, 0), make_float2(c1, 0), 2);    // RY wire1
    __syncthreads();
    float c2 = cosf(0.5f * th2), s2 = sinf(0.5f * th2);
    apply_1q(A, B, t, make_float2(c2, -s2), make_float2(0, 0),
                      make_float2(0, 0), make_float2(c2, s2), 1);    // RZ wire2
    __syncthreads();
    float c3 = cosf(0.5f * th3), s3 = sinf(0.5f * th3);
    apply_ctrl(B, A, t, make_float2(c3, 0), make_float2(0, -s3),
                        make_float2(0, -s3), make_float2(c3, 0), 3, 0); // CRX w0->w3
    __syncthreads();
    const float hh = 0.70710678118654752440f;
    apply_1q(A, B, t, make_float2(hh, 0), make_float2(hh, 0),
                      make_float2(hh, 0), make_float2(-hh, 0), 0);   // H wire3
    __syncthreads();
    apply_1q(B, A, t, make_float2(0.5f, 0.5f), make_float2(0.5f, -0.5f),
                      make_float2(0.5f, -0.5f), make_float2(0.5f, 0.5f), 1); // SX wire2
    __syncthreads();
    apply_ctrl(A, B, t, make_float2(0, 0), make_float2(1, 0),
                        make_float2(1, 0), make_float2(0, 0), 0, 3); // CX w3->w0
    __syncthreads();
    Ms[t] = B[t];
    __syncthreads();

    // ---- per-sample: BN1 -> encoder product state -> M*psi -> <Z_w> ----
    const int sidx = blockIdx.x * 256 + t;
    float4 o4 = ((const float4*)out_pre)[sidx];
    float ang[4] = {o4.x, o4.y, o4.z, o4.w};
    float2 v[4][2];
    #pragma unroll
    for (int w = 0; w < 4; ++w) {
        float a = fmaf(ss1[w], ang[w], ss1[4 + w]);
        float s, c;
        __sincosf(0.5f * a, &s, &c);
        float2 v0 = make_float2(c * c, -c * s);   // RZ after RY|0> = (c,s)
        float2 v1 = make_float2(s * c, s * s);
        float2 n0 = make_float2(c * v0.x + s * v1.y, c * v0.y - s * v1.x);   // RX
        float2 n1 = make_float2(s * v0.y + c * v1.x, -s * v0.x + c * v1.y);
        v[w][0] = make_float2(c * n0.x - s * n1.x, c * n0.y - s * n1.y);     // RY
        v[w][1] = make_float2(s * n0.x + c * n1.x, s * n0.y + c * n1.y);
    }
    float2 st[16];
    #pragma unroll
    for (int idx = 0; idx < 16; ++idx) {
        float2 p = cmul(v[0][(idx >> 3) & 1], v[1][(idx >> 2) & 1]);
        p = cmul(p, v[2][(idx >> 1) & 1]);
        st[idx] = cmul(p, v[3][idx & 1]);
    }
    float q[4] = {0.f, 0.f, 0.f, 0.f};
    #pragma unroll
    for (int j = 0; j < 16; ++j) {
        float2 acc = make_float2(0.f, 0.f);
        #pragma unroll
        for (int i = 0; i < 16; ++i) {
            float2 mm = Ms[j * 16 + i];
            acc.x = fmaf(mm.x, st[i].x, acc.x);
            acc.x = fmaf(-mm.y, st[i].y, acc.x);
            acc.y = fmaf(mm.x, st[i].y, acc.y);
            acc.y = fmaf(mm.y, st[i].x, acc.y);
        }
        float pr = acc.x * acc.x + acc.y * acc.y;
        q[0] += ((j >> 3) & 1) ? -pr : pr;
        q[1] += ((j >> 2) & 1) ? -pr : pr;
        q[2] += ((j >> 1) & 1) ? -pr : pr;
        q[3] += (j & 1) ? -pr : pr;
    }
    ((float4*)q_pre)[sidx] = make_float4(q[0], q[1], q[2], q[3]);

    // ---- BN2 partials: wave shuffle reduce -> LDS -> one row per block ----
    float vals[8] = {q[0], q[1], q[2], q[3],
                     q[0] * q[0], q[1] * q[1], q[2] * q[2], q[3] * q[3]};
    #pragma unroll
    for (int off = 32; off > 0; off >>= 1)
        #pragma unroll
        for (int k = 0; k < 8; ++k) vals[k] += __shfl_down(vals[k], off);
    __syncthreads();                      // Ms reads done; reuse red[]
    if ((t & 63) == 0) {
        int wid = t >> 6;
        #pragma unroll
        for (int k = 0; k < 8; ++k) red[wid * 8 + k] = vals[k];
    }
    __syncthreads();
    if (t < 8) {
        float s = red[t] + red[8 + t] + red[16 + t] + red[24 + t];
        bins2[blockIdx.x * 8 + t] = s;
    }
}

// ================= K3: reduce bins + final combine (in-place) ==============
__global__ __launch_bounds__(256) void k_final(
    float* __restrict__ out_pre,          // == d_out, [8192,4]
    const float* __restrict__ q_pre,
    const float* __restrict__ bins1, const float* __restrict__ bins2,
    const float* __restrict__ ng, const float* __restrict__ nb,
    const float* __restrict__ qg, const float* __restrict__ qb)
{
    __shared__ float red[512];
    __shared__ float ssA[8], ssB[8];
    const int t = threadIdx.x;
    red[t] = bins1[t];
    red[256 + t] = bins2[t];
    __syncthreads();
    if (t < 8) {
        float s1 = 0.f, s2 = 0.f;
        for (int bb = 0; bb < 32; ++bb) {
            s1 += red[bb * 8 + t];
            s2 += red[256 + bb * 8 + t];
        }
        red[t] = s1;
        red[8 + t] = s2;
    }
    if (t < 4) {
        float m1 = red[t] * (1.f / 8192.f);
        float v1 = red[4 + t] * (1.f / 8192.f) - m1 * m1;
        float sc1 = ng[t] * rsqrtf(v1 + 1e-5f);
        ssA[t] = sc1; ssA[4 + t] = nb[t] - m1 * sc1;
        float m2 = red[8 + t] * (1.f / 8192.f);
        float v2 = red[12 + t] * (1.f / 8192.f) - m2 * m2;
        float sc2 = qg[t] * rsqrtf(v2 + 1e-5f);
        ssB[t] = sc2; ssB[4 + t] = qb[t] - m2 * sc2;
    }
    __syncthreads();
    const int i = blockIdx.x * 256 + t;   // over 8192 float4 rows
    float4 o = ((const float4*)out_pre)[i];
    float4 q = ((const float4*)q_pre)[i];
    o.x = fmaf(ssA[0], o.x, ssA[4]) + fmaf(ssB[0], q.x, ssB[4]);
    o.y = fmaf(ssA[1], o.y, ssA[5]) + fmaf(ssB[1], q.y, ssB[5]);
    o.z = fmaf(ssA[2], o.z, ssA[6]) + fmaf(ssB[2], q.z, ssB[6]);
    o.w = fmaf(ssA[3], o.w, ssA[7]) + fmaf(ssB[3], q.w, ssB[7]);
    ((float4*)out_pre)[i] = o;
}

// ===========================================================================
extern "C" void kernel_launch(void* const* d_in, const int* in_sizes, int n_in,
                              void* d_out, int out_size, void* d_ws, size_t ws_size,
                              hipStream_t stream)
{
    const float* x     = (const float*)d_in[0];
    const float* w1    = (const float*)d_in[1];
    const float* b1    = (const float*)d_in[2];
    const float* w2    = (const float*)d_in[3];
    const float* b2    = (const float*)d_in[4];
    const float* fw1   = (const float*)d_in[5];
    const float* fb1   = (const float*)d_in[6];
    const float* fw2   = (const float*)d_in[7];
    const float* fb2   = (const float*)d_in[8];
    const float* ng    = (const float*)d_in[9];
    const float* nb    = (const float*)d_in[10];
    const float* theta = (const float*)d_in[11];
    const float* ure   = (const float*)d_in[12];
    const float* uim   = (const float*)d_in[13];
    const float* qg    = (const float*)d_in[14];
    const float* qb    = (const float*)d_in[15];

    float* out_pre = (float*)d_out;
    float* ws    = (float*)d_ws;
    float* bins1 = ws;            // 256 floats (32 bins x [sum4|sumsq4])
    float* bins2 = ws + 256;      // 256 floats (32 blocks x 8)
    float* q_pre = ws + 512;      // 32768 floats

    hipMemsetAsync(d_ws, 0, 2048, stream);
    k_cnn<<<8192, 256, 0, stream>>>(x, w1, b1, w2, b2, fw1, fb1, fw2, fb2,
                                    out_pre, bins1);
    k_quantum<<<32, 256, 0, stream>>>(out_pre, bins1, ng, nb, theta, ure, uim,
                                      q_pre, bins2);
    k_final<<<32, 256, 0, stream>>>(out_pre, q_pre, bins1, bins2, ng, nb, qg, qb);
}

// Round 3
// 231.742 us; speedup vs baseline: 1.8274x; 1.5280x over previous
//
#include <hip/hip_runtime.h>
#include <math.h>

// ---------------------------------------------------------------------------
// EstimatorQNNHybrid, round 3: broadcast-friendly conv task mapping.
//   conv1: 196 threads = (py,px); each computes all 8 ch (weights broadcast).
//   conv2: 196 threads = (pos, ocg); each computes float4 of 4 oc for one
//          pooled pixel; weights [ic][k][16oc] -> 1x ds_read_b128, 4 distinct
//          addrs/wave on disjoint bank quads. Patch reads 4-lane broadcast.
//   tail:  pool with 64 lanes + shfl_xor; fc1+fc2 in wave 0 (shuffle reduce).
// LDS row strides: xs 34, h1 18 (2*stride mod 32 = 4 -> spread), h2 49.
// ---------------------------------------------------------------------------

#define XS_S 34      // padded 30x34 input tile
#define H1_S 18      // padded 16x18 per-channel conv1 output
#define FW1_S 17

__device__ __forceinline__ float2 cmul(float2 a, float2 b) {
    return make_float2(a.x * b.x - a.y * b.y, a.x * b.y + a.y * b.x);
}
__device__ __forceinline__ float2 cadd(float2 a, float2 b) {
    return make_float2(a.x + b.x, a.y + b.y);
}

// ========================= K1: fused CNN per sample =========================
__global__ __launch_bounds__(256) void k_cnn(
    const float* __restrict__ x,
    const float* __restrict__ w1, const float* __restrict__ b1,
    const float* __restrict__ w2, const float* __restrict__ b2,
    const float* __restrict__ fw1, const float* __restrict__ fb1,
    const float* __restrict__ fw2, const float* __restrict__ fb2,
    float* __restrict__ out_pre, float* __restrict__ bins1)
{
    __shared__ __align__(16) float xs[30 * XS_S];        // 1020
    __shared__ __align__(16) float h1s[8 * 16 * H1_S];   // 2304
    __shared__ __align__(16) float h2s[16 * 49];         // 784
    __shared__ __align__(16) float w1t[72];              // [k][8c]
    __shared__ __align__(16) float w2t[72 * 16];         // [ic*9+k][16oc]
    __shared__ float b1s[8], b2s[16];
    __shared__ float fw1s[64 * FW1_S];                   // 1088
    __shared__ float pool_s[16];

    const int t = threadIdx.x;
    const int b = blockIdx.x;
    const float* xg = x + b * 784;

    // ---- phase A: zero xs + stage conv weights ----
    for (int i = t; i < 30 * XS_S; i += 256) xs[i] = 0.f;
    for (int i = t; i < 72; i += 256) { int c = i / 9, k = i % 9; w1t[k * 8 + c] = w1[i]; }
    for (int i = t; i < 1152; i += 256) {
        int oc = i / 72, rem = i % 72, ic = rem / 9, k = rem % 9;
        w2t[(ic * 9 + k) * 16 + oc] = w2[i];
    }
    if (t < 8)  b1s[t] = b1[t];
    if (t < 16) b2s[t] = b2[t];
    __syncthreads();

    // ---- phase B: fill xs interior + zero h1s ----
    for (int i = t; i < 784; i += 256) {
        int yy = i / 28, xx = i % 28;
        xs[(yy + 1) * XS_S + xx + 1] = xg[i];
    }
    for (int i = t; i < 8 * 16 * H1_S; i += 256) h1s[i] = 0.f;
    __syncthreads();

    // ---- conv1 (1->8) + relu + 2x2 maxpool: 196 threads = (py,px) ----
    if (t < 196) {
        const int py = t / 14, px = t % 14;
        float patch[4][4];
        #pragma unroll
        for (int dr = 0; dr < 4; ++dr) {
            int base = (2 * py + dr) * XS_S + 2 * px;
            float2 a = *(const float2*)&xs[base];
            float2 c = *(const float2*)&xs[base + 2];
            patch[dr][0] = a.x; patch[dr][1] = a.y;
            patch[dr][2] = c.x; patch[dr][3] = c.y;
        }
        float acc[8][2][2];
        #pragma unroll
        for (int c = 0; c < 8; ++c)
            #pragma unroll
            for (int dy = 0; dy < 2; ++dy)
                #pragma unroll
                for (int dx = 0; dx < 2; ++dx) acc[c][dy][dx] = 0.f;
        #pragma unroll
        for (int k = 0; k < 9; ++k) {
            const int ky = k / 3, kx = k % 3;
            float4 wA = *(const float4*)&w1t[k * 8];       // broadcast
            float4 wB = *(const float4*)&w1t[k * 8 + 4];
            float w8[8] = {wA.x, wA.y, wA.z, wA.w, wB.x, wB.y, wB.z, wB.w};
            #pragma unroll
            for (int c = 0; c < 8; ++c)
                #pragma unroll
                for (int dy = 0; dy < 2; ++dy)
                    #pragma unroll
                    for (int dx = 0; dx < 2; ++dx)
                        acc[c][dy][dx] = fmaf(patch[dy + ky][dx + kx], w8[c], acc[c][dy][dx]);
        }
        #pragma unroll
        for (int c = 0; c < 8; ++c) {
            float m = fmaxf(fmaxf(acc[c][0][0], acc[c][0][1]),
                            fmaxf(acc[c][1][0], acc[c][1][1])) + b1s[c];
            h1s[c * 16 * H1_S + (py + 1) * H1_S + (px + 1)] = fmaxf(m, 0.f);
        }
    } else if (t >= 200) {
        // idle lanes stage fc1 weights during conv1
        for (int i = t - 200; i < 1024; i += 56)
            fw1s[(i >> 4) * FW1_S + (i & 15)] = fw1[i];
    }
    __syncthreads();

    // ---- conv2 (8->16) + relu + 2x2 maxpool: 196 threads = (pos,ocg) ----
    if (t < 196) {
        const int pos = t >> 2, ocg = t & 3;
        const int py = pos / 7, px = pos % 7;
        float acc[4][4];    // [j][dy*2+dx]
        #pragma unroll
        for (int j = 0; j < 4; ++j)
            #pragma unroll
            for (int p = 0; p < 4; ++p) acc[j][p] = 0.f;
        #pragma unroll 2
        for (int ic = 0; ic < 8; ++ic) {
            float patch[4][4];
            #pragma unroll
            for (int dr = 0; dr < 4; ++dr) {
                int base = ic * 16 * H1_S + (2 * py + dr) * H1_S + 2 * px;
                float2 a = *(const float2*)&h1s[base];
                float2 c = *(const float2*)&h1s[base + 2];
                patch[dr][0] = a.x; patch[dr][1] = a.y;
                patch[dr][2] = c.x; patch[dr][3] = c.y;
            }
            #pragma unroll
            for (int k = 0; k < 9; ++k) {
                const int ky = k / 3, kx = k % 3;
                float4 w4 = *(const float4*)&w2t[(ic * 9 + k) * 16 + (ocg << 2)];
                float wj[4] = {w4.x, w4.y, w4.z, w4.w};
                #pragma unroll
                for (int j = 0; j < 4; ++j)
                    #pragma unroll
                    for (int dy = 0; dy < 2; ++dy)
                        #pragma unroll
                        for (int dx = 0; dx < 2; ++dx)
                            acc[j][dy * 2 + dx] = fmaf(patch[dy + ky][dx + kx], wj[j], acc[j][dy * 2 + dx]);
            }
        }
        #pragma unroll
        for (int j = 0; j < 4; ++j) {
            int oc = (ocg << 2) + j;
            float m = fmaxf(fmaxf(acc[j][0], acc[j][1]), fmaxf(acc[j][2], acc[j][3])) + b2s[oc];
            h2s[oc * 49 + pos] = fmaxf(m, 0.f);
        }
    }
    __syncthreads();

    // ---- avg over [:6,:6]: 64 lanes (wave 0), 9 elems each + shfl ----
    if (t < 64) {
        const int oc = t >> 2, q = t & 3;
        float s = 0.f;
        #pragma unroll
        for (int r = 0; r < 9; ++r) {
            int i = q * 9 + r;                   // 0..35
            s += h2s[oc * 49 + (i / 6) * 7 + (i % 6)];
        }
        s += __shfl_xor(s, 1);
        s += __shfl_xor(s, 2);
        if (q == 0) pool_s[oc] = s * (1.f / 36.f);
    }
    __syncthreads();

    // ---- fc1 (16->64) + relu + fc2 (64->4) entirely in wave 0 ----
    if (t < 64) {
        float a1 = fb1[t];
        #pragma unroll
        for (int c = 0; c < 16; ++c) a1 = fmaf(pool_s[c], fw1s[t * FW1_S + c], a1);
        float f = fmaxf(a1, 0.f);
        float p0 = f * fw2[t];
        float p1 = f * fw2[64 + t];
        float p2 = f * fw2[128 + t];
        float p3 = f * fw2[192 + t];
        #pragma unroll
        for (int off = 32; off > 0; off >>= 1) {
            p0 += __shfl_down(p0, off);
            p1 += __shfl_down(p1, off);
            p2 += __shfl_down(p2, off);
            p3 += __shfl_down(p3, off);
        }
        if (t == 0) {
            float v0 = p0 + fb2[0], v1 = p1 + fb2[1], v2 = p2 + fb2[2], v3 = p3 + fb2[3];
            ((float4*)out_pre)[b] = make_float4(v0, v1, v2, v3);
            float* bin = bins1 + ((b & 31) << 3);
            atomicAdd(&bin[0], v0);            atomicAdd(&bin[1], v1);
            atomicAdd(&bin[2], v2);            atomicAdd(&bin[3], v3);
            atomicAdd(&bin[4], v0 * v0);       atomicAdd(&bin[5], v1 * v1);
            atomicAdd(&bin[6], v2 * v2);       atomicAdd(&bin[7], v3 * v3);
        }
    }
}

// ================= helpers for fixed-gate folding ==========================
__device__ __forceinline__ void apply_1q(const float2* src, float2* dst, int t,
                                         float2 g00, float2 g01, float2 g10, float2 g11, int p)
{
    int j = t >> 4, i = t & 15;
    int jb = (j >> p) & 1;
    int k0 = j & ~(1 << p);
    int k1 = j | (1 << p);
    float2 a0 = src[k0 * 16 + i], a1 = src[k1 * 16 + i];
    float2 r = jb ? cadd(cmul(g10, a0), cmul(g11, a1))
                  : cadd(cmul(g00, a0), cmul(g01, a1));
    dst[j * 16 + i] = r;
}

__device__ __forceinline__ void apply_ctrl(const float2* src, float2* dst, int t,
                                           float2 g00, float2 g01, float2 g10, float2 g11,
                                           int pc, int pt)
{
    int j = t >> 4, i = t & 15;
    float2 r;
    if (((j >> pc) & 1) == 0) {
        r = src[j * 16 + i];
    } else {
        int jb = (j >> pt) & 1;
        int k0 = j & ~(1 << pt);
        int k1 = j | (1 << pt);
        float2 a0 = src[k0 * 16 + i], a1 = src[k1 * 16 + i];
        r = jb ? cadd(cmul(g10, a0), cmul(g11, a1))
               : cadd(cmul(g00, a0), cmul(g01, a1));
    }
    dst[j * 16 + i] = r;
}

// ====== K2: BN1 reduce + M build + per-sample quantum + BN2 partials =======
__global__ __launch_bounds__(256) void k_quantum(
    const float* __restrict__ out_pre,
    const float* __restrict__ bins1,
    const float* __restrict__ ng, const float* __restrict__ nb,
    const float* __restrict__ theta,
    const float* __restrict__ u_re, const float* __restrict__ u_im,
    float* __restrict__ q_pre, float* __restrict__ bins2)
{
    __shared__ float red[256];
    __shared__ float ss1[8];
    __shared__ float2 A[256], B[256];
    __shared__ float2 Ms[256];
    const int t = threadIdx.x;

    red[t] = bins1[t];
    A[t] = make_float2(u_re[t], u_im[t]);
    float th0 = theta[0], th1 = theta[1], th2 = theta[2], th3 = theta[3];
    __syncthreads();

    if (t < 8) {
        float s = 0.f;
        for (int bb = 0; bb < 32; ++bb) s += red[bb * 8 + t];
        red[t] = s;
    }
    if (t < 4) {
        float mean = red[t] * (1.f / 8192.f);
        float var = red[4 + t] * (1.f / 8192.f) - mean * mean;
        float sc = ng[t] * rsqrtf(var + 1e-5f);
        ss1[t] = sc;
        ss1[4 + t] = nb[t] - mean * sc;
    }

    // fold fixed tail: M = CX * SX * H * CRX * RZ * RY * RX * U
    float c0 = cosf(0.5f * th0), s0 = sinf(0.5f * th0);
    apply_1q(A, B, t, make_float2(c0, 0), make_float2(0, -s0),
                      make_float2(0, -s0), make_float2(c0, 0), 3);   // RX wire0
    __syncthreads();
    float c1 = cosf(0.5f * th1), s1 = sinf(0.5f * th1);
    apply_1q(B, A, t, make_float2(c1, 0), make_float2(-s1, 0),
                      make_float2(s1, 0), make_float2(c1, 0), 2);    // RY wire1
    __syncthreads();
    float c2 = cosf(0.5f * th2), s2 = sinf(0.5f * th2);
    apply_1q(A, B, t, make_float2(c2, -s2), make_float2(0, 0),
                      make_float2(0, 0), make_float2(c2, s2), 1);    // RZ wire2
    __syncthreads();
    float c3 = cosf(0.5f * th3), s3 = sinf(0.5f * th3);
    apply_ctrl(B, A, t, make_float2(c3, 0), make_float2(0, -s3),
                        make_float2(0, -s3), make_float2(c3, 0), 3, 0); // CRX w0->w3
    __syncthreads();
    const float hh = 0.70710678118654752440f;
    apply_1q(A, B, t, make_float2(hh, 0), make_float2(hh, 0),
                      make_float2(hh, 0), make_float2(-hh, 0), 0);   // H wire3
    __syncthreads();
    apply_1q(B, A, t, make_float2(0.5f, 0.5f), make_float2(0.5f, -0.5f),
                      make_float2(0.5f, -0.5f), make_float2(0.5f, 0.5f), 1); // SX wire2
    __syncthreads();
    apply_ctrl(A, B, t, make_float2(0, 0), make_float2(1, 0),
                        make_float2(1, 0), make_float2(0, 0), 0, 3); // CX w3->w0
    __syncthreads();
    Ms[t] = B[t];
    __syncthreads();

    // ---- per-sample: BN1 -> encoder product state -> M*psi -> <Z_w> ----
    const int sidx = blockIdx.x * 256 + t;
    float4 o4 = ((const float4*)out_pre)[sidx];
    float ang[4] = {o4.x, o4.y, o4.z, o4.w};
    float2 v[4][2];
    #pragma unroll
    for (int w = 0; w < 4; ++w) {
        float a = fmaf(ss1[w], ang[w], ss1[4 + w]);
        float s, c;
        __sincosf(0.5f * a, &s, &c);
        float2 v0 = make_float2(c * c, -c * s);
        float2 v1 = make_float2(s * c, s * s);
        float2 n0 = make_float2(c * v0.x + s * v1.y, c * v0.y - s * v1.x);
        float2 n1 = make_float2(s * v0.y + c * v1.x, -s * v0.x + c * v1.y);
        v[w][0] = make_float2(c * n0.x - s * n1.x, c * n0.y - s * n1.y);
        v[w][1] = make_float2(s * n0.x + c * n1.x, s * n0.y + c * n1.y);
    }
    float2 st[16];
    #pragma unroll
    for (int idx = 0; idx < 16; ++idx) {
        float2 p = cmul(v[0][(idx >> 3) & 1], v[1][(idx >> 2) & 1]);
        p = cmul(p, v[2][(idx >> 1) & 1]);
        st[idx] = cmul(p, v[3][idx & 1]);
    }
    float q[4] = {0.f, 0.f, 0.f, 0.f};
    #pragma unroll
    for (int j = 0; j < 16; ++j) {
        float2 acc = make_float2(0.f, 0.f);
        #pragma unroll
        for (int i = 0; i < 16; ++i) {
            float2 mm = Ms[j * 16 + i];
            acc.x = fmaf(mm.x, st[i].x, acc.x);
            acc.x = fmaf(-mm.y, st[i].y, acc.x);
            acc.y = fmaf(mm.x, st[i].y, acc.y);
            acc.y = fmaf(mm.y, st[i].x, acc.y);
        }
        float pr = acc.x * acc.x + acc.y * acc.y;
        q[0] += ((j >> 3) & 1) ? -pr : pr;
        q[1] += ((j >> 2) & 1) ? -pr : pr;
        q[2] += ((j >> 1) & 1) ? -pr : pr;
        q[3] += (j & 1) ? -pr : pr;
    }
    ((float4*)q_pre)[sidx] = make_float4(q[0], q[1], q[2], q[3]);

    // ---- BN2 partials ----
    float vals[8] = {q[0], q[1], q[2], q[3],
                     q[0] * q[0], q[1] * q[1], q[2] * q[2], q[3] * q[3]};
    #pragma unroll
    for (int off = 32; off > 0; off >>= 1)
        #pragma unroll
        for (int k = 0; k < 8; ++k) vals[k] += __shfl_down(vals[k], off);
    __syncthreads();
    if ((t & 63) == 0) {
        int wid = t >> 6;
        #pragma unroll
        for (int k = 0; k < 8; ++k) red[wid * 8 + k] = vals[k];
    }
    __syncthreads();
    if (t < 8) {
        float s = red[t] + red[8 + t] + red[16 + t] + red[24 + t];
        bins2[blockIdx.x * 8 + t] = s;
    }
}

// ================= K3: reduce bins + final combine (in-place) ==============
__global__ __launch_bounds__(256) void k_final(
    float* __restrict__ out_pre,
    const float* __restrict__ q_pre,
    const float* __restrict__ bins1, const float* __restrict__ bins2,
    const float* __restrict__ ng, const float* __restrict__ nb,
    const float* __restrict__ qg, const float* __restrict__ qb)
{
    __shared__ float red[512];
    __shared__ float ssA[8], ssB[8];
    const int t = threadIdx.x;
    red[t] = bins1[t];
    red[256 + t] = bins2[t];
    __syncthreads();
    if (t < 8) {
        float s1 = 0.f, s2 = 0.f;
        for (int bb = 0; bb < 32; ++bb) {
            s1 += red[bb * 8 + t];
            s2 += red[256 + bb * 8 + t];
        }
        red[t] = s1;
        red[8 + t] = s2;
    }
    if (t < 4) {
        float m1 = red[t] * (1.f / 8192.f);
        float v1 = red[4 + t] * (1.f / 8192.f) - m1 * m1;
        float sc1 = ng[t] * rsqrtf(v1 + 1e-5f);
        ssA[t] = sc1; ssA[4 + t] = nb[t] - m1 * sc1;
        float m2 = red[8 + t] * (1.f / 8192.f);
        float v2 = red[12 + t] * (1.f / 8192.f) - m2 * m2;
        float sc2 = qg[t] * rsqrtf(v2 + 1e-5f);
        ssB[t] = sc2; ssB[4 + t] = qb[t] - m2 * sc2;
    }
    __syncthreads();
    const int i = blockIdx.x * 256 + t;
    float4 o = ((const float4*)out_pre)[i];
    float4 q = ((const float4*)q_pre)[i];
    o.x = fmaf(ssA[0], o.x, ssA[4]) + fmaf(ssB[0], q.x, ssB[4]);
    o.y = fmaf(ssA[1], o.y, ssA[5]) + fmaf(ssB[1], q.y, ssB[5]);
    o.z = fmaf(ssA[2], o.z, ssA[6]) + fmaf(ssB[2], q.z, ssB[6]);
    o.w = fmaf(ssA[3], o.w, ssA[7]) + fmaf(ssB[3], q.w, ssB[7]);
    ((float4*)out_pre)[i] = o;
}

// ===========================================================================
extern "C" void kernel_launch(void* const* d_in, const int* in_sizes, int n_in,
                              void* d_out, int out_size, void* d_ws, size_t ws_size,
                              hipStream_t stream)
{
    const float* x     = (const float*)d_in[0];
    const float* w1    = (const float*)d_in[1];
    const float* b1    = (const float*)d_in[2];
    const float* w2    = (const float*)d_in[3];
    const float* b2    = (const float*)d_in[4];
    const float* fw1   = (const float*)d_in[5];
    const float* fb1   = (const float*)d_in[6];
    const float* fw2   = (const float*)d_in[7];
    const float* fb2   = (const float*)d_in[8];
    const float* ng    = (const float*)d_in[9];
    const float* nb    = (const float*)d_in[10];
    const float* theta = (const float*)d_in[11];
    const float* ure   = (const float*)d_in[12];
    const float* uim   = (const float*)d_in[13];
    const float* qg    = (const float*)d_in[14];
    const float* qb    = (const float*)d_in[15];

    float* out_pre = (float*)d_out;
    float* ws    = (float*)d_ws;
    float* bins1 = ws;            // 256 floats
    float* bins2 = ws + 256;      // 256 floats
    float* q_pre = ws + 512;      // 32768 floats

    hipMemsetAsync(d_ws, 0, 2048, stream);
    k_cnn<<<8192, 256, 0, stream>>>(x, w1, b1, w2, b2, fw1, fb1, fw2, fb2,
                                    out_pre, bins1);
    k_quantum<<<32, 256, 0, stream>>>(out_pre, bins1, ng, nb, theta, ure, uim,
                                      q_pre, bins2);
    k_final<<<32, 256, 0, stream>>>(out_pre, q_pre, bins1, bins2, ng, nb, qg, qb);
}

// Round 4
// 224.902 us; speedup vs baseline: 1.8830x; 1.0304x over previous
//
#include <hip/hip_runtime.h>
#include <math.h>

// ---------------------------------------------------------------------------
// EstimatorQNNHybrid, round 4: scalar-pipe weights (s_load K$) for convs,
// conv2 thread=pre-pool pos with acc[16], compute only the 12x12/13x13
// region consumed by the 6x6 avg-pool, k_prep pre-transposes w2 + builds M.
//   K0 k_prep    : zero bins, w2 -> [ic*9+k][16oc] in ws, fold fixed gates -> M
//   K1 k_cnn     : per-sample CNN -> out_pre (d_out) + atomic BN1 partials
//   K2 k_quantum : BN1 reduce + encoder product state + M*psi -> q_pre + BN2
//   K3 k_final   : reduce bins -> d_out = bn1(out_pre)+bn2(q_pre)
// ws: bins1[256] bins2[256] M[512] w2t[1152] q_pre[32768] = 140,800 B.
// ---------------------------------------------------------------------------

#define XS_S 34      // padded 30x34 input tile (only rows/cols 0..27 read)
#define H1_S 18      // padded 16x18 per-channel conv1 output

__device__ __forceinline__ float2 cmul(float2 a, float2 b) {
    return make_float2(a.x * b.x - a.y * b.y, a.x * b.y + a.y * b.x);
}
__device__ __forceinline__ float2 cadd(float2 a, float2 b) {
    return make_float2(a.x + b.x, a.y + b.y);
}

// ================= gate helpers (fixed-tail folding) ========================
__device__ __forceinline__ void apply_1q(const float2* src, float2* dst, int t,
                                         float2 g00, float2 g01, float2 g10, float2 g11, int p)
{
    int j = t >> 4, i = t & 15;
    int jb = (j >> p) & 1;
    int k0 = j & ~(1 << p);
    int k1 = j | (1 << p);
    float2 a0 = src[k0 * 16 + i], a1 = src[k1 * 16 + i];
    float2 r = jb ? cadd(cmul(g10, a0), cmul(g11, a1))
                  : cadd(cmul(g00, a0), cmul(g01, a1));
    dst[j * 16 + i] = r;
}

__device__ __forceinline__ void apply_ctrl(const float2* src, float2* dst, int t,
                                           float2 g00, float2 g01, float2 g10, float2 g11,
                                           int pc, int pt)
{
    int j = t >> 4, i = t & 15;
    float2 r;
    if (((j >> pc) & 1) == 0) {
        r = src[j * 16 + i];
    } else {
        int jb = (j >> pt) & 1;
        int k0 = j & ~(1 << pt);
        int k1 = j | (1 << pt);
        float2 a0 = src[k0 * 16 + i], a1 = src[k1 * 16 + i];
        r = jb ? cadd(cmul(g10, a0), cmul(g11, a1))
               : cadd(cmul(g00, a0), cmul(g01, a1));
    }
    dst[j * 16 + i] = r;
}

// ========== K0: zero bins + transpose w2 + build fused matrix M ============
__global__ __launch_bounds__(256) void k_prep(
    const float* __restrict__ w2, const float* __restrict__ theta,
    const float* __restrict__ u_re, const float* __restrict__ u_im,
    float* __restrict__ ws)
{
    __shared__ float2 A[256], B[256];
    const int t = threadIdx.x;
    ws[t] = 0.f;            // bins1
    ws[256 + t] = 0.f;      // bins2
    for (int i = t; i < 1152; i += 256) {
        int oc = i / 72, rem = i % 72;        // rem = ic*9+k
        ws[1024 + rem * 16 + oc] = w2[i];
    }
    A[t] = make_float2(u_re[t], u_im[t]);
    float th0 = theta[0], th1 = theta[1], th2 = theta[2], th3 = theta[3];
    __syncthreads();
    float c0 = cosf(0.5f * th0), s0 = sinf(0.5f * th0);
    apply_1q(A, B, t, make_float2(c0, 0), make_float2(0, -s0),
                      make_float2(0, -s0), make_float2(c0, 0), 3);   // RX wire0
    __syncthreads();
    float c1 = cosf(0.5f * th1), s1 = sinf(0.5f * th1);
    apply_1q(B, A, t, make_float2(c1, 0), make_float2(-s1, 0),
                      make_float2(s1, 0), make_float2(c1, 0), 2);    // RY wire1
    __syncthreads();
    float c2 = cosf(0.5f * th2), s2 = sinf(0.5f * th2);
    apply_1q(A, B, t, make_float2(c2, -s2), make_float2(0, 0),
                      make_float2(0, 0), make_float2(c2, s2), 1);    // RZ wire2
    __syncthreads();
    float c3 = cosf(0.5f * th3), s3 = sinf(0.5f * th3);
    apply_ctrl(B, A, t, make_float2(c3, 0), make_float2(0, -s3),
                        make_float2(0, -s3), make_float2(c3, 0), 3, 0); // CRX w0->w3
    __syncthreads();
    const float hh = 0.70710678118654752440f;
    apply_1q(A, B, t, make_float2(hh, 0), make_float2(hh, 0),
                      make_float2(hh, 0), make_float2(-hh, 0), 0);   // H wire3
    __syncthreads();
    apply_1q(B, A, t, make_float2(0.5f, 0.5f), make_float2(0.5f, -0.5f),
                      make_float2(0.5f, -0.5f), make_float2(0.5f, 0.5f), 1); // SX wire2
    __syncthreads();
    apply_ctrl(A, B, t, make_float2(0, 0), make_float2(1, 0),
                        make_float2(1, 0), make_float2(0, 0), 0, 3); // CX w3->w0
    __syncthreads();
    ws[512 + 2 * t]     = B[t].x;
    ws[512 + 2 * t + 1] = B[t].y;
}

// ========================= K1: fused CNN per sample =========================
__global__ __launch_bounds__(256) void k_cnn(
    const float* __restrict__ x,
    const float* __restrict__ w1, const float* __restrict__ b1,
    const float* __restrict__ w2t, const float* __restrict__ b2,
    const float* __restrict__ fw1, const float* __restrict__ fb1,
    const float* __restrict__ fw2, const float* __restrict__ fb2,
    float* __restrict__ out_pre, float* __restrict__ bins1)
{
    __shared__ __align__(16) float xs[30 * XS_S];        // 1020 (rows 0..29)
    __shared__ __align__(16) float h1s[8 * 16 * H1_S];   // 2304
    __shared__ __align__(16) float h2p[144 * 16];        // pre-pool conv2 [pos][16oc]
    __shared__ float pool_s[16];

    const int t = threadIdx.x;
    const int b = blockIdx.x;
    const float* xg = x + b * 784;

    // ---- phase A: pad borders + fill interior (all disjoint; one barrier) --
    if (t < 59) {                       // xs row 0 (cols 0..29) + col 0 (rows 1..29)
        if (t < 30) xs[t] = 0.f;
        else        xs[(t - 29) * XS_S] = 0.f;
    }
    if (t < 216) {                      // h1 borders: per plane row 0 (14) + col 0 (13)
        int pl = t / 27, r = t % 27;
        if (r < 14) h1s[pl * 288 + r] = 0.f;
        else        h1s[pl * 288 + (r - 13) * H1_S] = 0.f;
    }
    if (t < 196) {                      // interior: 196 float4 loads
        float4 v = ((const float4*)xg)[t];
        int p = t * 4;
        int yy = p / 28, xx = p % 28;   // 28 % 4 == 0 -> no row wrap
        int base = (yy + 1) * XS_S + xx + 1;
        xs[base]     = v.x;
        xs[base + 1] = v.y;
        xs[base + 2] = v.z;
        xs[base + 3] = v.w;
    }
    __syncthreads();

    // ---- conv1 (1->8) + relu + 2x2 maxpool: 169 threads = (py,px) 13x13 ----
    // weights w1[c*9+k] are wave-uniform -> scalar pipe (s_load), no LDS.
    if (t < 169) {
        const int py = t / 13, px = t % 13;
        float patch[4][4];
        #pragma unroll
        for (int dr = 0; dr < 4; ++dr) {
            int base = (2 * py + dr) * XS_S + 2 * px;       // even -> 8B aligned
            float2 a = *(const float2*)&xs[base];
            float2 c = *(const float2*)&xs[base + 2];
            patch[dr][0] = a.x; patch[dr][1] = a.y;
            patch[dr][2] = c.x; patch[dr][3] = c.y;
        }
        float acc[8][2][2];
        #pragma unroll
        for (int c = 0; c < 8; ++c)
            #pragma unroll
            for (int dy = 0; dy < 2; ++dy)
                #pragma unroll
                for (int dx = 0; dx < 2; ++dx) acc[c][dy][dx] = 0.f;
        #pragma unroll
        for (int k = 0; k < 9; ++k) {
            const int ky = k / 3, kx = k % 3;
            #pragma unroll
            for (int c = 0; c < 8; ++c) {
                float w = w1[c * 9 + k];                    // scalar (uniform)
                #pragma unroll
                for (int dy = 0; dy < 2; ++dy)
                    #pragma unroll
                    for (int dx = 0; dx < 2; ++dx)
                        acc[c][dy][dx] = fmaf(patch[dy + ky][dx + kx], w, acc[c][dy][dx]);
            }
        }
        #pragma unroll
        for (int c = 0; c < 8; ++c) {
            float m = fmaxf(fmaxf(acc[c][0][0], acc[c][0][1]),
                            fmaxf(acc[c][1][0], acc[c][1][1])) + b1[c];
            h1s[c * 288 + (py + 1) * H1_S + (px + 1)] = fmaxf(m, 0.f);
        }
    }
    __syncthreads();

    // ---- conv2 (8->16): 144 threads = pre-pool pos (y,x) in 12x12 ----------
    // acc[16] = all output channels; weights via scalar pipe from w2t.
    if (t < 144) {
        const int y = t / 12, x = t % 12;
        const int x0 = x & ~1;
        const bool odd = (x & 1) != 0;
        float acc[16];
        #pragma unroll
        for (int oc = 0; oc < 16; ++oc) acc[oc] = 0.f;
        #pragma unroll
        for (int ic = 0; ic < 8; ++ic) {
            float p[3][4];
            #pragma unroll
            for (int dr = 0; dr < 3; ++dr) {
                int base = ic * 288 + (y + dr) * H1_S + x0;  // even -> aligned
                float2 a = *(const float2*)&h1s[base];
                float2 c = *(const float2*)&h1s[base + 2];
                p[dr][0] = a.x; p[dr][1] = a.y; p[dr][2] = c.x; p[dr][3] = c.y;
            }
            float pv[9];
            #pragma unroll
            for (int dr = 0; dr < 3; ++dr)
                #pragma unroll
                for (int j = 0; j < 3; ++j)
                    pv[dr * 3 + j] = odd ? p[dr][j + 1] : p[dr][j];
            #pragma unroll
            for (int k = 0; k < 9; ++k) {
                const float* wrow = w2t + (ic * 9 + k) * 16;  // uniform -> s_load
                #pragma unroll
                for (int oc = 0; oc < 16; ++oc)
                    acc[oc] = fmaf(pv[k], wrow[oc], acc[oc]);
            }
        }
        const int hbase = t * 16;
        #pragma unroll
        for (int j = 0; j < 4; ++j)
            *(float4*)&h2p[hbase + 4 * j] =
                make_float4(acc[4 * j], acc[4 * j + 1], acc[4 * j + 2], acc[4 * j + 3]);
    }
    __syncthreads();

    // ---- maxpool(2x2) + bias + relu + avg 6x6: 64 lanes (wave 0) -----------
    if (t < 64) {
        const int oc = t >> 2, q = t & 3;
        const float bias = b2[oc];
        float s = 0.f;
        #pragma unroll
        for (int r = 0; r < 9; ++r) {
            int idx = q * 9 + r;                 // 0..35
            int pr = idx / 6, pc = idx % 6;
            int p00 = (2 * pr * 12 + 2 * pc) * 16 + oc;
            float m = fmaxf(fmaxf(h2p[p00], h2p[p00 + 16]),
                            fmaxf(h2p[p00 + 192], h2p[p00 + 208]));
            s += fmaxf(m + bias, 0.f);
        }
        s += __shfl_xor(s, 1);
        s += __shfl_xor(s, 2);
        if (q == 0) pool_s[oc] = s * (1.f / 36.f);
    }
    __syncthreads();

    // ---- fc1 (16->64) + relu + fc2 (64->4) in wave 0 -----------------------
    if (t < 64) {
        const float4* f4 = (const float4*)(fw1 + t * 16);
        float4 wa = f4[0], wb = f4[1], wc = f4[2], wd = f4[3];
        float a1 = fb1[t];
        a1 = fmaf(pool_s[0],  wa.x, a1); a1 = fmaf(pool_s[1],  wa.y, a1);
        a1 = fmaf(pool_s[2],  wa.z, a1); a1 = fmaf(pool_s[3],  wa.w, a1);
        a1 = fmaf(pool_s[4],  wb.x, a1); a1 = fmaf(pool_s[5],  wb.y, a1);
        a1 = fmaf(pool_s[6],  wb.z, a1); a1 = fmaf(pool_s[7],  wb.w, a1);
        a1 = fmaf(pool_s[8],  wc.x, a1); a1 = fmaf(pool_s[9],  wc.y, a1);
        a1 = fmaf(pool_s[10], wc.z, a1); a1 = fmaf(pool_s[11], wc.w, a1);
        a1 = fmaf(pool_s[12], wd.x, a1); a1 = fmaf(pool_s[13], wd.y, a1);
        a1 = fmaf(pool_s[14], wd.z, a1); a1 = fmaf(pool_s[15], wd.w, a1);
        float f = fmaxf(a1, 0.f);
        float p0 = f * fw2[t];
        float p1 = f * fw2[64 + t];
        float p2 = f * fw2[128 + t];
        float p3 = f * fw2[192 + t];
        #pragma unroll
        for (int off = 32; off > 0; off >>= 1) {
            p0 += __shfl_down(p0, off);
            p1 += __shfl_down(p1, off);
            p2 += __shfl_down(p2, off);
            p3 += __shfl_down(p3, off);
        }
        if (t == 0) {
            float v0 = p0 + fb2[0], v1 = p1 + fb2[1], v2 = p2 + fb2[2], v3 = p3 + fb2[3];
            ((float4*)out_pre)[b] = make_float4(v0, v1, v2, v3);
            float* bin = bins1 + ((b & 31) << 3);
            atomicAdd(&bin[0], v0);            atomicAdd(&bin[1], v1);
            atomicAdd(&bin[2], v2);            atomicAdd(&bin[3], v3);
            atomicAdd(&bin[4], v0 * v0);       atomicAdd(&bin[5], v1 * v1);
            atomicAdd(&bin[6], v2 * v2);       atomicAdd(&bin[7], v3 * v3);
        }
    }
}

// ====== K2: BN1 reduce + per-sample quantum + BN2 partials =================
__global__ __launch_bounds__(256) void k_quantum(
    const float* __restrict__ out_pre,
    const float* __restrict__ bins1,
    const float* __restrict__ ng, const float* __restrict__ nb,
    const float* __restrict__ Mg,
    float* __restrict__ q_pre, float* __restrict__ bins2)
{
    __shared__ float red[256];
    __shared__ float ss1[8];
    __shared__ float2 Ms[256];
    const int t = threadIdx.x;

    red[t] = bins1[t];
    Ms[t] = make_float2(Mg[2 * t], Mg[2 * t + 1]);
    __syncthreads();
    if (t < 8) {
        float s = 0.f;
        for (int bb = 0; bb < 32; ++bb) s += red[bb * 8 + t];
        red[t] = s;
    }
    if (t < 4) {
        float mean = red[t] * (1.f / 8192.f);
        float var = red[4 + t] * (1.f / 8192.f) - mean * mean;
        float sc = ng[t] * rsqrtf(var + 1e-5f);
        ss1[t] = sc;
        ss1[4 + t] = nb[t] - mean * sc;
    }
    __syncthreads();

    const int sidx = blockIdx.x * 256 + t;
    float4 o4 = ((const float4*)out_pre)[sidx];
    float ang[4] = {o4.x, o4.y, o4.z, o4.w};
    float2 v[4][2];
    #pragma unroll
    for (int w = 0; w < 4; ++w) {
        float a = fmaf(ss1[w], ang[w], ss1[4 + w]);
        float s, c;
        __sincosf(0.5f * a, &s, &c);
        float2 v0 = make_float2(c * c, -c * s);
        float2 v1 = make_float2(s * c, s * s);
        float2 n0 = make_float2(c * v0.x + s * v1.y, c * v0.y - s * v1.x);
        float2 n1 = make_float2(s * v0.y + c * v1.x, -s * v0.x + c * v1.y);
        v[w][0] = make_float2(c * n0.x - s * n1.x, c * n0.y - s * n1.y);
        v[w][1] = make_float2(s * n0.x + c * n1.x, s * n0.y + c * n1.y);
    }
    float2 st[16];
    #pragma unroll
    for (int idx = 0; idx < 16; ++idx) {
        float2 p = cmul(v[0][(idx >> 3) & 1], v[1][(idx >> 2) & 1]);
        p = cmul(p, v[2][(idx >> 1) & 1]);
        st[idx] = cmul(p, v[3][idx & 1]);
    }
    float q[4] = {0.f, 0.f, 0.f, 0.f};
    #pragma unroll
    for (int j = 0; j < 16; ++j) {
        float2 acc = make_float2(0.f, 0.f);
        #pragma unroll
        for (int i = 0; i < 16; ++i) {
            float2 mm = Ms[j * 16 + i];
            acc.x = fmaf(mm.x, st[i].x, acc.x);
            acc.x = fmaf(-mm.y, st[i].y, acc.x);
            acc.y = fmaf(mm.x, st[i].y, acc.y);
            acc.y = fmaf(mm.y, st[i].x, acc.y);
        }
        float pr = acc.x * acc.x + acc.y * acc.y;
        q[0] += ((j >> 3) & 1) ? -pr : pr;
        q[1] += ((j >> 2) & 1) ? -pr : pr;
        q[2] += ((j >> 1) & 1) ? -pr : pr;
        q[3] += (j & 1) ? -pr : pr;
    }
    ((float4*)q_pre)[sidx] = make_float4(q[0], q[1], q[2], q[3]);

    float vals[8] = {q[0], q[1], q[2], q[3],
                     q[0] * q[0], q[1] * q[1], q[2] * q[2], q[3] * q[3]};
    #pragma unroll
    for (int off = 32; off > 0; off >>= 1)
        #pragma unroll
        for (int k = 0; k < 8; ++k) vals[k] += __shfl_down(vals[k], off);
    __syncthreads();
    if ((t & 63) == 0) {
        int wid = t >> 6;
        #pragma unroll
        for (int k = 0; k < 8; ++k) red[wid * 8 + k] = vals[k];
    }
    __syncthreads();
    if (t < 8) {
        float s = red[t] + red[8 + t] + red[16 + t] + red[24 + t];
        bins2[blockIdx.x * 8 + t] = s;
    }
}

// ================= K3: reduce bins + final combine (in-place) ==============
__global__ __launch_bounds__(256) void k_final(
    float* __restrict__ out_pre,
    const float* __restrict__ q_pre,
    const float* __restrict__ bins1, const float* __restrict__ bins2,
    const float* __restrict__ ng, const float* __restrict__ nb,
    const float* __restrict__ qg, const float* __restrict__ qb)
{
    __shared__ float red[512];
    __shared__ float ssA[8], ssB[8];
    const int t = threadIdx.x;
    red[t] = bins1[t];
    red[256 + t] = bins2[t];
    __syncthreads();
    if (t < 8) {
        float s1 = 0.f, s2 = 0.f;
        for (int bb = 0; bb < 32; ++bb) {
            s1 += red[bb * 8 + t];
            s2 += red[256 + bb * 8 + t];
        }
        red[t] = s1;
        red[8 + t] = s2;
    }
    if (t < 4) {
        float m1 = red[t] * (1.f / 8192.f);
        float v1 = red[4 + t] * (1.f / 8192.f) - m1 * m1;
        float sc1 = ng[t] * rsqrtf(v1 + 1e-5f);
        ssA[t] = sc1; ssA[4 + t] = nb[t] - m1 * sc1;
        float m2 = red[8 + t] * (1.f / 8192.f);
        float v2 = red[12 + t] * (1.f / 8192.f) - m2 * m2;
        float sc2 = qg[t] * rsqrtf(v2 + 1e-5f);
        ssB[t] = sc2; ssB[4 + t] = qb[t] - m2 * sc2;
    }
    __syncthreads();
    const int i = blockIdx.x * 256 + t;
    float4 o = ((const float4*)out_pre)[i];
    float4 q = ((const float4*)q_pre)[i];
    o.x = fmaf(ssA[0], o.x, ssA[4]) + fmaf(ssB[0], q.x, ssB[4]);
    o.y = fmaf(ssA[1], o.y, ssA[5]) + fmaf(ssB[1], q.y, ssB[5]);
    o.z = fmaf(ssA[2], o.z, ssA[6]) + fmaf(ssB[2], q.z, ssB[6]);
    o.w = fmaf(ssA[3], o.w, ssA[7]) + fmaf(ssB[3], q.w, ssB[7]);
    ((float4*)out_pre)[i] = o;
}

// ===========================================================================
extern "C" void kernel_launch(void* const* d_in, const int* in_sizes, int n_in,
                              void* d_out, int out_size, void* d_ws, size_t ws_size,
                              hipStream_t stream)
{
    const float* x     = (const float*)d_in[0];
    const float* w1    = (const float*)d_in[1];
    const float* b1    = (const float*)d_in[2];
    const float* w2    = (const float*)d_in[3];
    const float* b2    = (const float*)d_in[4];
    const float* fw1   = (const float*)d_in[5];
    const float* fb1   = (const float*)d_in[6];
    const float* fw2   = (const float*)d_in[7];
    const float* fb2   = (const float*)d_in[8];
    const float* ng    = (const float*)d_in[9];
    const float* nb    = (const float*)d_in[10];
    const float* theta = (const float*)d_in[11];
    const float* ure   = (const float*)d_in[12];
    const float* uim   = (const float*)d_in[13];
    const float* qg    = (const float*)d_in[14];
    const float* qb    = (const float*)d_in[15];

    float* ws    = (float*)d_ws;
    float* bins1 = ws;            // 256
    float* bins2 = ws + 256;      // 256
    float* Mg    = ws + 512;      // 512
    float* w2t   = ws + 1024;     // 1152
    float* q_pre = ws + 2432;     // 32768
    float* out_pre = (float*)d_out;

    k_prep<<<1, 256, 0, stream>>>(w2, theta, ure, uim, ws);
    k_cnn<<<8192, 256, 0, stream>>>(x, w1, b1, w2t, b2, fw1, fb1, fw2, fb2,
                                    out_pre, bins1);
    k_quantum<<<32, 256, 0, stream>>>(out_pre, bins1, ng, nb, Mg, q_pre, bins2);
    k_final<<<32, 256, 0, stream>>>(out_pre, q_pre, bins1, bins2, ng, nb, qg, qb);
}